// Round 2
// baseline (529.742 us; speedup 1.0000x reference)
//
#include <hip/hip_runtime.h>

// EdgeNet: BN -> inputnet MLP -> EdgeConv(linearized) -> mean-pool -> output MLP
// Shapes: N=50000 nodes, E=1.6M edges, D=13, H=32, G=128 graphs. All I/O float32.
// Key restructure: m = [x_i, x_j-x_i]@W1 = x_i@(Wtop-Wbot) + x_j@Wbot
//   => per-node A = feat@(Wtop-Wbot)+b1, B = feat@Wbot (stored bf16), per-edge only
//      h = relu(A[dst]+B[src]); out = tanh(h@W2+b2) via MFMA 16x16x32 bf16.

typedef __attribute__((ext_vector_type(4))) float floatx4;
typedef __attribute__((ext_vector_type(8))) short short8;

__device__ __forceinline__ unsigned short f2bf(float f) {
    unsigned int u = __float_as_uint(f);
    u += 0x7FFFu + ((u >> 16) & 1u);   // RTNE
    return (unsigned short)(u >> 16);
}
__device__ __forceinline__ float fast_tanh(float x) {
    float ax = fminf(fabsf(x), 20.0f);
    float t = __expf(-2.0f * ax);
    float r = (1.0f - t) / (1.0f + t);
    return copysignf(r, x);
}
__device__ __forceinline__ float fast_sigmoid(float x) {
    float xc = fminf(fmaxf(x, -30.f), 30.f);
    return 1.0f / (1.0f + __expf(-xc));
}

// ---------------- K1: BatchNorm statistics ----------------
__global__ __launch_bounds__(256) void k_bnstat(const float* __restrict__ x,
                                                int N, float* __restrict__ bns) {
    int tid = blockIdx.x * blockDim.x + threadIdx.x;
    int stride = gridDim.x * blockDim.x;
    float s[13], q[13];
#pragma unroll
    for (int d = 0; d < 13; d++) { s[d] = 0.f; q[d] = 0.f; }
    for (int n = tid; n < N; n += stride) {
        const float* row = x + (size_t)n * 13;
#pragma unroll
        for (int d = 0; d < 13; d++) { float f = row[d]; s[d] += f; q[d] += f * f; }
    }
#pragma unroll
    for (int d = 0; d < 13; d++) {
        for (int off = 32; off > 0; off >>= 1) {
            s[d] += __shfl_down(s[d], off, 64);
            q[d] += __shfl_down(q[d], off, 64);
        }
    }
    if ((threadIdx.x & 63) == 0) {
#pragma unroll
        for (int d = 0; d < 13; d++) {
            unsafeAtomicAdd(&bns[d], s[d]);
            unsafeAtomicAdd(&bns[13 + d], q[d]);
        }
    }
}

// ---------------- K1b: finalize scale/shift ----------------
__global__ void k_bnfin(const float* __restrict__ bns, const float* __restrict__ g,
                        const float* __restrict__ b, float* __restrict__ scl, float invN) {
    int d = threadIdx.x;
    if (d < 13) {
        float mu  = bns[d] * invN;
        float var = fmaxf(bns[13 + d] * invN - mu * mu, 0.f);
        float sc  = g[d] / sqrtf(var + 1e-5f);
        scl[d]      = sc;
        scl[16 + d] = b[d] - mu * sc;
    }
}

// ---------------- K2: per-node phase ----------------
// X = bn(x); h1 = relu(X@W1+b1); h2 = tanh(h1@W2+b2); feat=[h2,X]
// A = feat@(Wtop-Wbot)+conv_b1; B = feat@Wbot  (both bf16, row-major [N,64])
// also: graph sums of X and node counts.
__global__ __launch_bounds__(256) void k_node(
    const float* __restrict__ x, const int* __restrict__ batch,
    const float* __restrict__ in_w1, const float* __restrict__ in_b1,
    const float* __restrict__ in_w2, const float* __restrict__ in_b2,
    const float* __restrict__ conv_w1, const float* __restrict__ conv_b1,
    const float* __restrict__ scl,
    unsigned short* __restrict__ A, unsigned short* __restrict__ Bm,
    float* __restrict__ gacc, int N) {
    __shared__ float sW1[13 * 32], sB1[32], sW2[32 * 32], sB2[32];
    __shared__ float sWd[45 * 64], sWb[45 * 64], sCb1[64];
    int tid = threadIdx.x;
    for (int i = tid; i < 13 * 32; i += 256) sW1[i] = in_w1[i];
    if (tid < 32) { sB1[tid] = in_b1[tid]; sB2[tid] = in_b2[tid]; }
    for (int i = tid; i < 32 * 32; i += 256) sW2[i] = in_w2[i];
    for (int i = tid; i < 45 * 64; i += 256) {
        float top = conv_w1[i];
        float bot = conv_w1[45 * 64 + i];
        sWd[i] = top - bot;
        sWb[i] = bot;
    }
    if (tid < 64) sCb1[tid] = conv_b1[tid];
    __syncthreads();

    int n = blockIdx.x * 256 + tid;
    if (n >= N) return;

    float X[13];
#pragma unroll
    for (int d = 0; d < 13; d++)
        X[d] = x[(size_t)n * 13 + d] * scl[d] + scl[16 + d];

    float h1[32];
#pragma unroll
    for (int j = 0; j < 32; j++) {
        float acc = sB1[j];
#pragma unroll
        for (int d = 0; d < 13; d++) acc += X[d] * sW1[d * 32 + j];
        h1[j] = fmaxf(acc, 0.f);
    }
    float h2[32];
#pragma unroll
    for (int j = 0; j < 32; j++) {
        float acc = sB2[j];
#pragma unroll
        for (int k = 0; k < 32; k++) acc += h1[k] * sW2[k * 32 + j];
        h2[j] = fast_tanh(acc);
    }

    // A, B rows (64 each), stored bf16, written 16B at a time
    for (int j0 = 0; j0 < 64; j0 += 8) {
        float av[8], bv[8];
#pragma unroll
        for (int jj = 0; jj < 8; jj++) {
            int j = j0 + jj;
            float a = sCb1[j], b = 0.f;
#pragma unroll
            for (int k = 0; k < 32; k++) { a += h2[k] * sWd[k * 64 + j]; b += h2[k] * sWb[k * 64 + j]; }
#pragma unroll
            for (int d = 0; d < 13; d++) { a += X[d] * sWd[(32 + d) * 64 + j]; b += X[d] * sWb[(32 + d) * 64 + j]; }
            av[jj] = a; bv[jj] = b;
        }
        uint4 ua, ub;
        ua.x = (unsigned)f2bf(av[0]) | ((unsigned)f2bf(av[1]) << 16);
        ua.y = (unsigned)f2bf(av[2]) | ((unsigned)f2bf(av[3]) << 16);
        ua.z = (unsigned)f2bf(av[4]) | ((unsigned)f2bf(av[5]) << 16);
        ua.w = (unsigned)f2bf(av[6]) | ((unsigned)f2bf(av[7]) << 16);
        ub.x = (unsigned)f2bf(bv[0]) | ((unsigned)f2bf(bv[1]) << 16);
        ub.y = (unsigned)f2bf(bv[2]) | ((unsigned)f2bf(bv[3]) << 16);
        ub.z = (unsigned)f2bf(bv[4]) | ((unsigned)f2bf(bv[5]) << 16);
        ub.w = (unsigned)f2bf(bv[6]) | ((unsigned)f2bf(bv[7]) << 16);
        *(uint4*)(A  + (size_t)n * 64 + j0) = ua;
        *(uint4*)(Bm + (size_t)n * 64 + j0) = ub;
    }

    int g = batch[n];
#pragma unroll
    for (int d = 0; d < 13; d++) unsafeAtomicAdd(&gacc[g * 46 + 32 + d], X[d]);
    unsafeAtomicAdd(&gacc[g * 46 + 45], 1.0f);
}

// ---------------- K3: edge phase (MFMA) ----------------
// 16 edges per wave. A-frag: A[m=lane&15][k=quad*8+j]. B-frag: W2[k=quad*8+j][n=lane&15].
// C/D: row(m)=quad*4+reg, col(n)=lane&15.
__global__ __launch_bounds__(256) void k_edge(
    const int* __restrict__ ei,
    const unsigned short* __restrict__ A, const unsigned short* __restrict__ Bm,
    const float* __restrict__ conv_w2, const float* __restrict__ conv_b2,
    float* __restrict__ Hn, int E) {
    int lane = threadIdx.x & 63;
    int wid  = blockIdx.x * (blockDim.x >> 6) + (threadIdx.x >> 6);
    int nw   = gridDim.x * (blockDim.x >> 6);
    int q = lane >> 4;
    int m = lane & 15;

    // weight B-fragments (held in registers for the whole kernel)
    short8 wf[2][2];
#pragma unroll
    for (int s = 0; s < 2; s++)
#pragma unroll
        for (int t = 0; t < 2; t++)
#pragma unroll
            for (int j = 0; j < 8; j++)
                wf[s][t][j] = (short)f2bf(conv_w2[(s * 32 + q * 8 + j) * 32 + t * 16 + m]);
    float cb2a = conv_b2[m];
    float cb2b = conv_b2[16 + m];

    const int* srcp = ei;
    const int* dstp = ei + E;
    int ngroups = E >> 4;

    for (int gI = wid; gI < ngroups; gI += nw) {
        int e0 = gI << 4;
        int vd = dstp[e0 + m];
        int vs = srcp[e0 + m];
        floatx4 c0 = {0.f, 0.f, 0.f, 0.f};
        floatx4 c1 = {0.f, 0.f, 0.f, 0.f};
#pragma unroll
        for (int ks = 0; ks < 2; ks++) {
            uint4 av = *(const uint4*)(A  + (size_t)vd * 64 + ks * 32 + q * 8);
            uint4 bv = *(const uint4*)(Bm + (size_t)vs * 64 + ks * 32 + q * 8);
            unsigned au[4] = {av.x, av.y, av.z, av.w};
            unsigned bu[4] = {bv.x, bv.y, bv.z, bv.w};
            short8 ha;
#pragma unroll
            for (int i = 0; i < 4; i++) {
                float a0 = __uint_as_float(au[i] << 16);
                float a1 = __uint_as_float(au[i] & 0xffff0000u);
                float b0 = __uint_as_float(bu[i] << 16);
                float b1 = __uint_as_float(bu[i] & 0xffff0000u);
                float h0 = fmaxf(a0 + b0, 0.f);
                float h1v = fmaxf(a1 + b1, 0.f);
                ha[2 * i]     = (short)f2bf(h0);
                ha[2 * i + 1] = (short)f2bf(h1v);
            }
            c0 = __builtin_amdgcn_mfma_f32_16x16x32_bf16(ha, wf[ks][0], c0, 0, 0, 0);
            c1 = __builtin_amdgcn_mfma_f32_16x16x32_bf16(ha, wf[ks][1], c1, 0, 0, 0);
        }
#pragma unroll
        for (int r = 0; r < 4; r++) {
            int m2 = (q << 2) + r;
            int dd = __shfl(vd, m2, 64);
            float o0 = fast_tanh(c0[r] + cb2a);
            float o1 = fast_tanh(c1[r] + cb2b);
            unsafeAtomicAdd(&Hn[(size_t)dd * 32 + m], o0);
            unsafeAtomicAdd(&Hn[(size_t)dd * 32 + 16 + m], o1);
        }
    }

    // scalar tail (E % 16 != 0); dead for E = 1.6M but kept for safety
    int tail = E & 15;
    if (tail && wid == 0 && lane < tail) {
        int e = (E & ~15) + lane;
        int vd = dstp[e], vs = srcp[e];
        float h[64];
        for (int k = 0; k < 64; k++) {
            float a = __uint_as_float((unsigned)A[(size_t)vd * 64 + k] << 16);
            float b = __uint_as_float((unsigned)Bm[(size_t)vs * 64 + k] << 16);
            h[k] = fmaxf(a + b, 0.f);
        }
        for (int j = 0; j < 32; j++) {
            float acc = conv_b2[j];
            for (int k = 0; k < 64; k++) acc += h[k] * conv_w2[k * 32 + j];
            unsafeAtomicAdd(&Hn[(size_t)vd * 32 + j], fast_tanh(acc));
        }
    }
}

// ---------------- K4: pool Hn into graph accumulators ----------------
// batch is sorted; segmented running sum per (thread, channel), flush on graph change.
__global__ __launch_bounds__(256) void k_pool(const float* __restrict__ Hn,
                                              const int* __restrict__ batch,
                                              float* __restrict__ gacc, int N) {
    const int NPB = 512;
    int c = threadIdx.x & 31;
    int r = threadIdx.x >> 5;  // 0..7
    int n0 = blockIdx.x * NPB;
    int nend = min(n0 + NPB, N);
    int gcur = -1;
    float acc = 0.f;
    for (int n = n0 + r; n < nend; n += 8) {
        int g = batch[n];
        if (g != gcur) {
            if (gcur >= 0) unsafeAtomicAdd(&gacc[gcur * 46 + c], acc);
            gcur = g; acc = 0.f;
        }
        acc += Hn[(size_t)n * 32 + c];
    }
    if (gcur >= 0) unsafeAtomicAdd(&gacc[gcur * 46 + c], acc);
}

// ---------------- K5: output MLP ----------------
__global__ void k_out(const float* __restrict__ gacc,
                      const float* __restrict__ out_w1, const float* __restrict__ out_b1,
                      const float* __restrict__ out_w2, const float* __restrict__ out_b2,
                      float* __restrict__ out, int G) {
    int g = blockIdx.x * blockDim.x + threadIdx.x;
    if (g >= G) return;
    float cnt = fmaxf(gacc[g * 46 + 45], 1.0f);
    float inv = 1.0f / cnt;
    float f[45];
#pragma unroll
    for (int i = 0; i < 45; i++) f[i] = gacc[g * 46 + i] * inv;
    float h[32];
#pragma unroll
    for (int j = 0; j < 32; j++) {
        float acc = out_b1[j];
#pragma unroll
        for (int k = 0; k < 45; k++) acc += f[k] * out_w1[k * 32 + j];
        h[j] = fmaxf(acc, 0.f);
    }
    float o = out_b2[0];
#pragma unroll
    for (int j = 0; j < 32; j++) o += h[j] * out_w2[j];
    out[g] = fast_sigmoid(o);
}

extern "C" void kernel_launch(void* const* d_in, const int* in_sizes, int n_in,
                              void* d_out, int out_size, void* d_ws, size_t ws_size,
                              hipStream_t stream) {
    const float* x      = (const float*)d_in[0];
    const int*   ei     = (const int*)d_in[1];
    const int*   batch  = (const int*)d_in[2];
    const float* bn_g   = (const float*)d_in[3];
    const float* bn_b   = (const float*)d_in[4];
    const float* in_w1  = (const float*)d_in[5];
    const float* in_b1  = (const float*)d_in[6];
    const float* in_w2  = (const float*)d_in[7];
    const float* in_b2  = (const float*)d_in[8];
    const float* cw1    = (const float*)d_in[9];
    const float* cb1    = (const float*)d_in[10];
    const float* cw2    = (const float*)d_in[11];
    const float* cb2    = (const float*)d_in[12];
    const float* ow1    = (const float*)d_in[13];
    const float* ob1    = (const float*)d_in[14];
    const float* ow2    = (const float*)d_in[15];
    const float* ob2    = (const float*)d_in[16];

    int N = in_sizes[0] / 13;
    int E = in_sizes[1] / 2;
    int G = out_size;

    auto al = [](size_t v) { return (v + 255) & ~(size_t)255; };
    char* ws = (char*)d_ws;
    size_t hn_off   = 0;
    size_t gacc_off = al((size_t)N * 32 * 4);
    size_t bns_off  = gacc_off + al((size_t)G * 46 * 4);
    size_t scl_off  = bns_off + 256;
    size_t a_off    = scl_off + 256;
    size_t b_off    = a_off + al((size_t)N * 64 * 2);

    float* Hn   = (float*)(ws + hn_off);
    float* gacc = (float*)(ws + gacc_off);
    float* bns  = (float*)(ws + bns_off);
    float* scl  = (float*)(ws + scl_off);
    unsigned short* A  = (unsigned short*)(ws + a_off);
    unsigned short* Bm = (unsigned short*)(ws + b_off);

    // zero Hn + gacc + bn accumulators (ws is poisoned 0xAA before each call)
    hipMemsetAsync(ws, 0, bns_off + 256, stream);

    k_bnstat<<<120, 256, 0, stream>>>(x, N, bns);
    k_bnfin<<<1, 64, 0, stream>>>(bns, bn_g, bn_b, scl, 1.0f / (float)N);
    k_node<<<(N + 255) / 256, 256, 0, stream>>>(x, batch, in_w1, in_b1, in_w2, in_b2,
                                                cw1, cb1, scl, A, Bm, gacc, N);
    k_edge<<<1024, 256, 0, stream>>>(ei, A, Bm, cw2, cb2, Hn, E);
    k_pool<<<(N + 511) / 512, 256, 0, stream>>>(Hn, batch, gacc, N);
    k_out<<<1, 128, 0, stream>>>(gacc, ow1, ob1, ow2, ob2, (float*)d_out, G);
}

// Round 4
// 525.334 us; speedup vs baseline: 1.0084x; 1.0084x over previous
//
#include <hip/hip_runtime.h>

// EdgeNet: BN -> inputnet MLP -> EdgeConv(linearized) -> mean-pool -> output MLP
// N=50000, E=1.6M, D=13, H=32, G=128. All I/O float32.
// EdgeConv restructure: m = [x_i, x_j-x_i]@W1 = x_i@(Wtop-Wbot) + x_j@Wbot
//   => per-node A = feat@(Wtop-Wbot)+b1, B = feat@Wbot (bf16), per-edge
//      h = relu(A[dst]+B[src]); msg = tanh(h@W2+b2) via MFMA 16x16x32 bf16.
// R4: Hn eliminated entirely — sum_{n in g} Hn[n] == sum_{e: batch[dst(e)]=g} msg(e),
//     so k_edge accumulates straight into a per-block LDS gacc replica (f32 LDS
//     atomics) and flushes 4096 global atomics/block. k_pool deleted.

typedef __attribute__((ext_vector_type(4))) float floatx4;
typedef __attribute__((ext_vector_type(8))) short short8;

__device__ __forceinline__ unsigned short f2bf(float f) {
    unsigned int u = __float_as_uint(f);
    u += 0x7FFFu + ((u >> 16) & 1u);   // RTNE
    return (unsigned short)(u >> 16);
}
__device__ __forceinline__ float fast_tanh(float x) {
    float ax = fminf(fabsf(x), 20.0f);
    float t = __expf(-2.0f * ax);
    float r = (1.0f - t) / (1.0f + t);
    return copysignf(r, x);
}
__device__ __forceinline__ float fast_sigmoid(float x) {
    float xc = fminf(fmaxf(x, -30.f), 30.f);
    return 1.0f / (1.0f + __expf(-xc));
}

// ---------------- K1: BatchNorm statistics ----------------
__global__ __launch_bounds__(256) void k_bnstat(const float* __restrict__ x,
                                                int N, float* __restrict__ bns) {
    int tid = blockIdx.x * blockDim.x + threadIdx.x;
    int stride = gridDim.x * blockDim.x;
    float s[13], q[13];
#pragma unroll
    for (int d = 0; d < 13; d++) { s[d] = 0.f; q[d] = 0.f; }
    for (int n = tid; n < N; n += stride) {
        const float* row = x + (size_t)n * 13;
#pragma unroll
        for (int d = 0; d < 13; d++) { float f = row[d]; s[d] += f; q[d] += f * f; }
    }
#pragma unroll
    for (int d = 0; d < 13; d++) {
        for (int off = 32; off > 0; off >>= 1) {
            s[d] += __shfl_down(s[d], off, 64);
            q[d] += __shfl_down(q[d], off, 64);
        }
    }
    if ((threadIdx.x & 63) == 0) {
#pragma unroll
        for (int d = 0; d < 13; d++) {
            unsafeAtomicAdd(&bns[d], s[d]);
            unsafeAtomicAdd(&bns[13 + d], q[d]);
        }
    }
}

// ---------------- K1b: finalize scale/shift ----------------
__global__ void k_bnfin(const float* __restrict__ bns, const float* __restrict__ g,
                        const float* __restrict__ b, float* __restrict__ scl, float invN) {
    int d = threadIdx.x;
    if (d < 13) {
        float mu  = bns[d] * invN;
        float var = fmaxf(bns[13 + d] * invN - mu * mu, 0.f);
        float sc  = g[d] / sqrtf(var + 1e-5f);
        scl[d]      = sc;
        scl[16 + d] = b[d] - mu * sc;
    }
}

// ---------------- K2: per-node phase ----------------
// phase0: stage weights (incl. Wcat^T bf16) in LDS
// phase1: per-thread X, h1, h2; feat row -> LDS (bf16, K padded to 64); gacc X-sums
// phase2: per-wave MFMA: feat[64x64] @ Wcat[64x128] -> A|B rows (bf16, global)
#define FP 72  // feat LDS row stride in shorts (64 + 8 pad)
#define WP 72  // WcatT LDS row stride in shorts
__global__ __launch_bounds__(256) void k_node(
    const float* __restrict__ x, const int* __restrict__ batch,
    const float* __restrict__ in_w1, const float* __restrict__ in_b1,
    const float* __restrict__ in_w2, const float* __restrict__ in_b2,
    const float* __restrict__ conv_w1, const float* __restrict__ conv_b1,
    const float* __restrict__ scl,
    unsigned short* __restrict__ A, unsigned short* __restrict__ Bm,
    float* __restrict__ gacc, int N) {
    __shared__ float sW1[13 * 32], sB1[32], sW2[32 * 32], sB2[32];
    __shared__ unsigned short sWcatT[128 * WP];  // [col c][k], bf16
    __shared__ unsigned short sFeat[256 * FP];   // [node row][k], bf16
    int tid = threadIdx.x;

    // ---- phase 0: weights to LDS ----
    for (int i = tid; i < 13 * 32; i += 256) sW1[i] = in_w1[i];
    if (tid < 32) { sB1[tid] = in_b1[tid]; sB2[tid] = in_b2[tid]; }
    for (int i = tid; i < 32 * 32; i += 256) sW2[i] = in_w2[i];
    // WcatT[c][k]: c<64 -> Wd[k][c]=top-bot ; c>=64 -> Wb[k][c-64]=bot ; k>=45 -> 0
    for (int i = tid; i < 128 * 64; i += 256) {
        int c = i >> 6, k = i & 63;
        float v = 0.f;
        if (k < 45) {
            int cc = c & 63;
            float bot = conv_w1[(45 + k) * 64 + cc];
            v = (c < 64) ? (conv_w1[k * 64 + cc] - bot) : bot;
        }
        sWcatT[c * WP + k] = f2bf(v);
    }
    __syncthreads();

    int n = blockIdx.x * 256 + tid;
    bool valid = (n < N);
    int nl = valid ? n : (N - 1);

    // ---- phase 1: per-thread MLP ----
    float X[13];
#pragma unroll
    for (int d = 0; d < 13; d++)
        X[d] = x[(size_t)nl * 13 + d] * scl[d] + scl[16 + d];
    float h1[32];
#pragma unroll
    for (int j = 0; j < 32; j++) {
        float acc = sB1[j];
#pragma unroll
        for (int d = 0; d < 13; d++) acc += X[d] * sW1[d * 32 + j];
        h1[j] = fmaxf(acc, 0.f);
    }
    float h2[32];
#pragma unroll
    for (int j = 0; j < 32; j++) {
        float acc = sB2[j];
#pragma unroll
        for (int k = 0; k < 32; k++) acc += h1[k] * sW2[k * 32 + j];
        h2[j] = fast_tanh(acc);
    }

    // feat row = [h2(32) | X(13) | zeros(19)] bf16 -> LDS
    unsigned int fw[16];
#pragma unroll
    for (int i = 0; i < 16; i++) fw[i] = 0;
    if (valid) {
#pragma unroll
        for (int i = 0; i < 16; i++)
            fw[i] = (unsigned)f2bf(h2[2 * i]) | ((unsigned)f2bf(h2[2 * i + 1]) << 16);
    }
    unsigned int xw[7];
#pragma unroll
    for (int i = 0; i < 7; i++) xw[i] = 0;
    if (valid) {
#pragma unroll
        for (int i = 0; i < 6; i++)
            xw[i] = (unsigned)f2bf(X[2 * i]) | ((unsigned)f2bf(X[2 * i + 1]) << 16);
        xw[6] = (unsigned)f2bf(X[12]);
    }
    {
        unsigned short* row = sFeat + tid * FP;
        ((uint4*)row)[0] = make_uint4(fw[0], fw[1], fw[2], fw[3]);
        ((uint4*)row)[1] = make_uint4(fw[4], fw[5], fw[6], fw[7]);
        ((uint4*)row)[2] = make_uint4(fw[8], fw[9], fw[10], fw[11]);
        ((uint4*)row)[3] = make_uint4(fw[12], fw[13], fw[14], fw[15]);
        ((uint4*)row)[4] = make_uint4(xw[0], xw[1], xw[2], xw[3]);
        ((uint4*)row)[5] = make_uint4(xw[4], xw[5], xw[6], 0u);
        ((uint4*)row)[6] = make_uint4(0u, 0u, 0u, 0u);
        ((uint4*)row)[7] = make_uint4(0u, 0u, 0u, 0u);
    }

    // ---- gacc: graph sums of X + count (wave-reduced when graph-uniform) ----
    {
        int g = valid ? batch[n] : -1;
        unsigned long long uni = __ballot(g == __shfl(g, 0, 64));
        if (uni == ~0ull && g >= 0) {
            float red[14];
#pragma unroll
            for (int d = 0; d < 13; d++) red[d] = X[d];
            red[13] = 1.0f;
#pragma unroll
            for (int d = 0; d < 14; d++)
                for (int off = 32; off > 0; off >>= 1)
                    red[d] += __shfl_down(red[d], off, 64);
            if ((tid & 63) == 0) {
#pragma unroll
                for (int d = 0; d < 13; d++) unsafeAtomicAdd(&gacc[g * 46 + 32 + d], red[d]);
                unsafeAtomicAdd(&gacc[g * 46 + 45], red[13]);
            }
        } else if (valid) {
#pragma unroll
            for (int d = 0; d < 13; d++) unsafeAtomicAdd(&gacc[g * 46 + 32 + d], X[d]);
            unsafeAtomicAdd(&gacc[g * 46 + 45], 1.0f);
        }
    }
    __syncthreads();

    // ---- phase 2: MFMA feat@Wcat ----
    int lane = tid & 63;
    int w = tid >> 6;        // wave id 0..3
    int q = lane >> 4;
    int m = lane & 15;

    short8 wf[2][8];  // [ks][col-tile]
#pragma unroll
    for (int ks = 0; ks < 2; ks++)
#pragma unroll
        for (int t = 0; t < 8; t++) {
            wf[ks][t] = *(const short8*)(sWcatT + (t * 16 + m) * WP + ks * 32 + q * 8);
        }
    float cb1v[4];
#pragma unroll
    for (int t = 0; t < 4; t++) cb1v[t] = conv_b1[t * 16 + m];

    int base = blockIdx.x * 256 + w * 64;
#pragma unroll
    for (int tile = 0; tile < 4; tile++) {
        const unsigned short* ar = sFeat + (w * 64 + tile * 16 + m) * FP;
        short8 a0 = *(const short8*)(ar + q * 8);
        short8 a1 = *(const short8*)(ar + 32 + q * 8);
        floatx4 c[8];
#pragma unroll
        for (int t = 0; t < 8; t++) {
            floatx4 z = {0.f, 0.f, 0.f, 0.f};
            c[t] = __builtin_amdgcn_mfma_f32_16x16x32_bf16(a0, wf[0][t], z, 0, 0, 0);
            c[t] = __builtin_amdgcn_mfma_f32_16x16x32_bf16(a1, wf[1][t], c[t], 0, 0, 0);
        }
        // C/D: col=m (within tile), row=q*4+r
#pragma unroll
        for (int r = 0; r < 4; r++) {
            int row = base + tile * 16 + (q << 2) + r;
            if (row < N) {
#pragma unroll
                for (int t = 0; t < 4; t++)
                    A[(size_t)row * 64 + t * 16 + m] = f2bf(c[t][r] + cb1v[t]);
#pragma unroll
                for (int t = 4; t < 8; t++)
                    Bm[(size_t)row * 64 + (t - 4) * 16 + m] = f2bf(c[t][r]);
            }
        }
    }
}

// ---------------- K3: edge phase (MFMA + LDS graph accumulation) ----------------
// 16 edges per wave. A-frag: h[m=lane&15][k=q*8+j]. B-frags hold W2 cols
// interleaved even/odd (tile0 col n -> 2n, tile1 -> 2n+1) so lane m's two C
// values are channels (2m, 2m+1) of edge row q*4+r.
// Messages accumulate into per-block LDS gacc replica [128 graphs x 32 ch],
// flushed once per block -> 4096 global atomics/block.
__global__ __launch_bounds__(512) void k_edge(
    const int* __restrict__ ei, const int* __restrict__ batch,
    const unsigned short* __restrict__ A, const unsigned short* __restrict__ Bm,
    const float* __restrict__ conv_w2, const float* __restrict__ conv_b2,
    float* __restrict__ gacc, int E, int G) {
    __shared__ float sg[128 * 32];
    int tid = threadIdx.x;
    for (int i = tid; i < 128 * 32; i += 512) sg[i] = 0.f;

    int lane = tid & 63;
    int wid  = blockIdx.x * (blockDim.x >> 6) + (tid >> 6);
    int nw   = gridDim.x * (blockDim.x >> 6);
    int q = lane >> 4;
    int m = lane & 15;

    short8 wf[2][2];
#pragma unroll
    for (int s = 0; s < 2; s++)
#pragma unroll
        for (int t = 0; t < 2; t++)
#pragma unroll
            for (int j = 0; j < 8; j++)
                wf[s][t][j] = (short)f2bf(conv_w2[(s * 32 + q * 8 + j) * 32 + 2 * m + t]);
    float cb2a = conv_b2[2 * m];
    float cb2b = conv_b2[2 * m + 1];
    __syncthreads();

    const int* srcp = ei;
    const int* dstp = ei + E;
    int ngroups = E >> 4;

    for (int gI = wid; gI < ngroups; gI += nw) {
        int e0 = gI << 4;
        int vd = dstp[e0 + m];
        int vs = srcp[e0 + m];
        int gv = batch[vd];
        floatx4 c0 = {0.f, 0.f, 0.f, 0.f};
        floatx4 c1 = {0.f, 0.f, 0.f, 0.f};
#pragma unroll
        for (int ks = 0; ks < 2; ks++) {
            uint4 av = *(const uint4*)(A  + (size_t)vd * 64 + ks * 32 + q * 8);
            uint4 bv = *(const uint4*)(Bm + (size_t)vs * 64 + ks * 32 + q * 8);
            unsigned au[4] = {av.x, av.y, av.z, av.w};
            unsigned bu[4] = {bv.x, bv.y, bv.z, bv.w};
            short8 ha;
#pragma unroll
            for (int i = 0; i < 4; i++) {
                float a0 = __uint_as_float(au[i] << 16);
                float a1 = __uint_as_float(au[i] & 0xffff0000u);
                float b0 = __uint_as_float(bu[i] << 16);
                float b1 = __uint_as_float(bu[i] & 0xffff0000u);
                float h0 = fmaxf(a0 + b0, 0.f);
                float h1v = fmaxf(a1 + b1, 0.f);
                ha[2 * i]     = (short)f2bf(h0);
                ha[2 * i + 1] = (short)f2bf(h1v);
            }
            c0 = __builtin_amdgcn_mfma_f32_16x16x32_bf16(ha, wf[ks][0], c0, 0, 0, 0);
            c1 = __builtin_amdgcn_mfma_f32_16x16x32_bf16(ha, wf[ks][1], c1, 0, 0, 0);
        }
#pragma unroll
        for (int r = 0; r < 4; r++) {
            int m2 = (q << 2) + r;
            int gg = __shfl(gv, m2, 64);
            float o0 = fast_tanh(c0[r] + cb2a);
            float o1 = fast_tanh(c1[r] + cb2b);
            atomicAdd(&sg[gg * 32 + 2 * m], o0);
            atomicAdd(&sg[gg * 32 + 2 * m + 1], o1);
        }
    }

    // scalar tail (E % 16): straight to global gacc
    int tail = E & 15;
    if (tail && wid == 0 && lane < tail) {
        int e = (E & ~15) + lane;
        int vd = dstp[e], vs = srcp[e];
        int gg = batch[vd];
        float h[64];
        for (int k = 0; k < 64; k++) {
            float a = __uint_as_float((unsigned)A[(size_t)vd * 64 + k] << 16);
            float b = __uint_as_float((unsigned)Bm[(size_t)vs * 64 + k] << 16);
            h[k] = fmaxf(a + b, 0.f);
        }
        for (int j = 0; j < 32; j++) {
            float acc = conv_b2[j];
            for (int k = 0; k < 64; k++) acc += h[k] * conv_w2[k * 32 + j];
            unsafeAtomicAdd(&gacc[gg * 46 + j], fast_tanh(acc));
        }
    }

    __syncthreads();
    for (int i = tid; i < 128 * 32; i += 512) {
        float v = sg[i];
        if (v != 0.f) unsafeAtomicAdd(&gacc[(i >> 5) * 46 + (i & 31)], v);
    }
}

// ---------------- K5: output MLP ----------------
__global__ void k_out(const float* __restrict__ gacc,
                      const float* __restrict__ out_w1, const float* __restrict__ out_b1,
                      const float* __restrict__ out_w2, const float* __restrict__ out_b2,
                      float* __restrict__ out, int G) {
    int g = blockIdx.x * blockDim.x + threadIdx.x;
    if (g >= G) return;
    float cnt = fmaxf(gacc[g * 46 + 45], 1.0f);
    float inv = 1.0f / cnt;
    float f[45];
#pragma unroll
    for (int i = 0; i < 45; i++) f[i] = gacc[g * 46 + i] * inv;
    float h[32];
#pragma unroll
    for (int j = 0; j < 32; j++) {
        float acc = out_b1[j];
#pragma unroll
        for (int k = 0; k < 45; k++) acc += f[k] * out_w1[k * 32 + j];
        h[j] = fmaxf(acc, 0.f);
    }
    float o = out_b2[0];
#pragma unroll
    for (int j = 0; j < 32; j++) o += h[j] * out_w2[j];
    out[g] = fast_sigmoid(o);
}

extern "C" void kernel_launch(void* const* d_in, const int* in_sizes, int n_in,
                              void* d_out, int out_size, void* d_ws, size_t ws_size,
                              hipStream_t stream) {
    const float* x      = (const float*)d_in[0];
    const int*   ei     = (const int*)d_in[1];
    const int*   batch  = (const int*)d_in[2];
    const float* bn_g   = (const float*)d_in[3];
    const float* bn_b   = (const float*)d_in[4];
    const float* in_w1  = (const float*)d_in[5];
    const float* in_b1  = (const float*)d_in[6];
    const float* in_w2  = (const float*)d_in[7];
    const float* in_b2  = (const float*)d_in[8];
    const float* cw1    = (const float*)d_in[9];
    const float* cb1    = (const float*)d_in[10];
    const float* cw2    = (const float*)d_in[11];
    const float* cb2    = (const float*)d_in[12];
    const float* ow1    = (const float*)d_in[13];
    const float* ob1    = (const float*)d_in[14];
    const float* ow2    = (const float*)d_in[15];
    const float* ob2    = (const float*)d_in[16];

    int N = in_sizes[0] / 13;
    int E = in_sizes[1] / 2;
    int G = out_size;
    int Npad = (N + 255) & ~255;

    auto al = [](size_t v) { return (v + 255) & ~(size_t)255; };
    char* ws = (char*)d_ws;
    size_t gacc_off = 0;
    size_t bns_off  = al((size_t)G * 46 * 4);
    size_t scl_off  = bns_off + 256;
    size_t a_off    = scl_off + 256;
    size_t b_off    = a_off + al((size_t)Npad * 64 * 2);

    float* gacc = (float*)(ws + gacc_off);
    float* bns  = (float*)(ws + bns_off);
    float* scl  = (float*)(ws + scl_off);
    unsigned short* A  = (unsigned short*)(ws + a_off);
    unsigned short* Bm = (unsigned short*)(ws + b_off);

    // zero gacc + bn accumulators (ws is poisoned 0xAA before each call)
    hipMemsetAsync(ws, 0, a_off, stream);

    k_bnstat<<<120, 256, 0, stream>>>(x, N, bns);
    k_bnfin<<<1, 64, 0, stream>>>(bns, bn_g, bn_b, scl, 1.0f / (float)N);
    k_node<<<(N + 255) / 256, 256, 0, stream>>>(x, batch, in_w1, in_b1, in_w2, in_b2,
                                                cw1, cb1, scl, A, Bm, gacc, N);
    k_edge<<<1024, 512, 0, stream>>>(ei, batch, A, Bm, cw2, cb2, gacc, E, G);
    k_out<<<1, 128, 0, stream>>>(gacc, ow1, ob1, ow2, ob2, (float*)d_out, G);
}

// Round 5
// 460.295 us; speedup vs baseline: 1.1509x; 1.1413x over previous
//
#include <hip/hip_runtime.h>

// EdgeNet: BN -> inputnet MLP -> EdgeConv(linearized) -> mean-pool -> output MLP
// N=50000, E=1.6M, D=13, H=32, G=128. All I/O float32.
// EdgeConv restructure: m = [x_i, x_j-x_i]@W1 = x_i@(Wtop-Wbot) + x_j@Wbot
//   => per-node A = feat@(Wtop-Wbot)+b1, B = feat@Wbot (bf16), per-edge
//      h = relu(A[dst]+B[src]); msg = tanh(h@W2+b2) via MFMA 16x16x32 bf16.
// R5: k_edge reverted to R2 structure (global f32 atomics to Hn = measured
//     atomic-rate ceiling, 169us; R4's LDS-atomic variant was 275us). k_pool
//     restored. k_node: MFMA version with 128-thread blocks (391 blocks, 43KB
//     LDS) to fix the 196-block/60KB-LDS fragility.

typedef __attribute__((ext_vector_type(4))) float floatx4;
typedef __attribute__((ext_vector_type(8))) short short8;

__device__ __forceinline__ unsigned short f2bf(float f) {
    unsigned int u = __float_as_uint(f);
    u += 0x7FFFu + ((u >> 16) & 1u);   // RTNE
    return (unsigned short)(u >> 16);
}
__device__ __forceinline__ float fast_tanh(float x) {
    float ax = fminf(fabsf(x), 20.0f);
    float t = __expf(-2.0f * ax);
    float r = (1.0f - t) / (1.0f + t);
    return copysignf(r, x);
}
__device__ __forceinline__ float fast_sigmoid(float x) {
    float xc = fminf(fmaxf(x, -30.f), 30.f);
    return 1.0f / (1.0f + __expf(-xc));
}

// ---------------- K1: BatchNorm statistics ----------------
__global__ __launch_bounds__(256) void k_bnstat(const float* __restrict__ x,
                                                int N, float* __restrict__ bns) {
    int tid = blockIdx.x * blockDim.x + threadIdx.x;
    int stride = gridDim.x * blockDim.x;
    float s[13], q[13];
#pragma unroll
    for (int d = 0; d < 13; d++) { s[d] = 0.f; q[d] = 0.f; }
    for (int n = tid; n < N; n += stride) {
        const float* row = x + (size_t)n * 13;
#pragma unroll
        for (int d = 0; d < 13; d++) { float f = row[d]; s[d] += f; q[d] += f * f; }
    }
#pragma unroll
    for (int d = 0; d < 13; d++) {
        for (int off = 32; off > 0; off >>= 1) {
            s[d] += __shfl_down(s[d], off, 64);
            q[d] += __shfl_down(q[d], off, 64);
        }
    }
    if ((threadIdx.x & 63) == 0) {
#pragma unroll
        for (int d = 0; d < 13; d++) {
            unsafeAtomicAdd(&bns[d], s[d]);
            unsafeAtomicAdd(&bns[13 + d], q[d]);
        }
    }
}

// ---------------- K1b: finalize scale/shift ----------------
__global__ void k_bnfin(const float* __restrict__ bns, const float* __restrict__ g,
                        const float* __restrict__ b, float* __restrict__ scl, float invN) {
    int d = threadIdx.x;
    if (d < 13) {
        float mu  = bns[d] * invN;
        float var = fmaxf(bns[13 + d] * invN - mu * mu, 0.f);
        float sc  = g[d] / sqrtf(var + 1e-5f);
        scl[d]      = sc;
        scl[16 + d] = b[d] - mu * sc;
    }
}

// ---------------- K2: per-node phase (128 threads / 128 nodes per block) ----
// phase0: stage weights (incl. Wcat^T bf16) in LDS
// phase1: per-thread X, h1, h2; feat row -> LDS (bf16, K padded to 64); gacc X-sums
// phase2: 2 waves x MFMA: feat[64x64] @ Wcat[64x128] -> A|B rows (bf16, global)
#define FP 72  // feat LDS row stride in shorts (64 + 8 pad)
#define WP 72  // WcatT LDS row stride in shorts
__global__ __launch_bounds__(128) void k_node(
    const float* __restrict__ x, const int* __restrict__ batch,
    const float* __restrict__ in_w1, const float* __restrict__ in_b1,
    const float* __restrict__ in_w2, const float* __restrict__ in_b2,
    const float* __restrict__ conv_w1, const float* __restrict__ conv_b1,
    const float* __restrict__ scl,
    unsigned short* __restrict__ A, unsigned short* __restrict__ Bm,
    float* __restrict__ gacc, int N) {
    __shared__ float sW1[13 * 32], sB1[32], sW2[32 * 32], sB2[32];
    __shared__ unsigned short sWcatT[128 * WP];  // [col c][k], bf16
    __shared__ unsigned short sFeat[128 * FP];   // [node row][k], bf16
    int tid = threadIdx.x;

    // ---- phase 0: weights to LDS ----
    for (int i = tid; i < 13 * 32; i += 128) sW1[i] = in_w1[i];
    if (tid < 32) { sB1[tid] = in_b1[tid]; sB2[tid] = in_b2[tid]; }
    for (int i = tid; i < 32 * 32; i += 128) sW2[i] = in_w2[i];
    // WcatT[c][k]: c<64 -> Wd[k][c]=top-bot ; c>=64 -> Wb[k][c-64]=bot ; k>=45 -> 0
    for (int i = tid; i < 128 * 64; i += 128) {
        int c = i >> 6, k = i & 63;
        float v = 0.f;
        if (k < 45) {
            int cc = c & 63;
            float bot = conv_w1[(45 + k) * 64 + cc];
            v = (c < 64) ? (conv_w1[k * 64 + cc] - bot) : bot;
        }
        sWcatT[c * WP + k] = f2bf(v);
    }
    __syncthreads();

    int n = blockIdx.x * 128 + tid;
    bool valid = (n < N);
    int nl = valid ? n : (N - 1);

    // ---- phase 1: per-thread MLP ----
    float X[13];
#pragma unroll
    for (int d = 0; d < 13; d++)
        X[d] = x[(size_t)nl * 13 + d] * scl[d] + scl[16 + d];
    float h1[32];
#pragma unroll
    for (int j = 0; j < 32; j++) {
        float acc = sB1[j];
#pragma unroll
        for (int d = 0; d < 13; d++) acc += X[d] * sW1[d * 32 + j];
        h1[j] = fmaxf(acc, 0.f);
    }
    float h2[32];
#pragma unroll
    for (int j = 0; j < 32; j++) {
        float acc = sB2[j];
#pragma unroll
        for (int k = 0; k < 32; k++) acc += h1[k] * sW2[k * 32 + j];
        h2[j] = fast_tanh(acc);
    }

    // feat row = [h2(32) | X(13) | zeros(19)] bf16 -> LDS
    unsigned int fw[16];
#pragma unroll
    for (int i = 0; i < 16; i++) fw[i] = 0;
    if (valid) {
#pragma unroll
        for (int i = 0; i < 16; i++)
            fw[i] = (unsigned)f2bf(h2[2 * i]) | ((unsigned)f2bf(h2[2 * i + 1]) << 16);
    }
    unsigned int xw[7];
#pragma unroll
    for (int i = 0; i < 7; i++) xw[i] = 0;
    if (valid) {
#pragma unroll
        for (int i = 0; i < 6; i++)
            xw[i] = (unsigned)f2bf(X[2 * i]) | ((unsigned)f2bf(X[2 * i + 1]) << 16);
        xw[6] = (unsigned)f2bf(X[12]);
    }
    {
        unsigned short* row = sFeat + tid * FP;
        ((uint4*)row)[0] = make_uint4(fw[0], fw[1], fw[2], fw[3]);
        ((uint4*)row)[1] = make_uint4(fw[4], fw[5], fw[6], fw[7]);
        ((uint4*)row)[2] = make_uint4(fw[8], fw[9], fw[10], fw[11]);
        ((uint4*)row)[3] = make_uint4(fw[12], fw[13], fw[14], fw[15]);
        ((uint4*)row)[4] = make_uint4(xw[0], xw[1], xw[2], xw[3]);
        ((uint4*)row)[5] = make_uint4(xw[4], xw[5], xw[6], 0u);
        ((uint4*)row)[6] = make_uint4(0u, 0u, 0u, 0u);
        ((uint4*)row)[7] = make_uint4(0u, 0u, 0u, 0u);
    }

    // ---- gacc: graph sums of X + count (wave-reduced when graph-uniform) ----
    {
        int g = valid ? batch[n] : -1;
        unsigned long long uni = __ballot(g == __shfl(g, 0, 64));
        if (uni == ~0ull && g >= 0) {
            float red[14];
#pragma unroll
            for (int d = 0; d < 13; d++) red[d] = X[d];
            red[13] = 1.0f;
#pragma unroll
            for (int d = 0; d < 14; d++)
                for (int off = 32; off > 0; off >>= 1)
                    red[d] += __shfl_down(red[d], off, 64);
            if ((tid & 63) == 0) {
#pragma unroll
                for (int d = 0; d < 13; d++) unsafeAtomicAdd(&gacc[g * 46 + 32 + d], red[d]);
                unsafeAtomicAdd(&gacc[g * 46 + 45], red[13]);
            }
        } else if (valid) {
#pragma unroll
            for (int d = 0; d < 13; d++) unsafeAtomicAdd(&gacc[g * 46 + 32 + d], X[d]);
            unsafeAtomicAdd(&gacc[g * 46 + 45], 1.0f);
        }
    }
    __syncthreads();

    // ---- phase 2: MFMA feat@Wcat (2 waves, 4 row-tiles each) ----
    int lane = tid & 63;
    int w = tid >> 6;        // wave id 0..1
    int q = lane >> 4;
    int m = lane & 15;

    short8 wf[2][8];  // [ks][col-tile]
#pragma unroll
    for (int ks = 0; ks < 2; ks++)
#pragma unroll
        for (int t = 0; t < 8; t++) {
            wf[ks][t] = *(const short8*)(sWcatT + (t * 16 + m) * WP + ks * 32 + q * 8);
        }
    float cb1v[4];
#pragma unroll
    for (int t = 0; t < 4; t++) cb1v[t] = conv_b1[t * 16 + m];

    int base = blockIdx.x * 128 + w * 64;
#pragma unroll
    for (int tile = 0; tile < 4; tile++) {
        const unsigned short* ar = sFeat + (w * 64 + tile * 16 + m) * FP;
        short8 a0 = *(const short8*)(ar + q * 8);
        short8 a1 = *(const short8*)(ar + 32 + q * 8);
        floatx4 c[8];
#pragma unroll
        for (int t = 0; t < 8; t++) {
            floatx4 z = {0.f, 0.f, 0.f, 0.f};
            c[t] = __builtin_amdgcn_mfma_f32_16x16x32_bf16(a0, wf[0][t], z, 0, 0, 0);
            c[t] = __builtin_amdgcn_mfma_f32_16x16x32_bf16(a1, wf[1][t], c[t], 0, 0, 0);
        }
        // C/D: col=m (within tile), row=q*4+r
#pragma unroll
        for (int r = 0; r < 4; r++) {
            int row = base + tile * 16 + (q << 2) + r;
            if (row < N) {
#pragma unroll
                for (int t = 0; t < 4; t++)
                    A[(size_t)row * 64 + t * 16 + m] = f2bf(c[t][r] + cb1v[t]);
#pragma unroll
                for (int t = 4; t < 8; t++)
                    Bm[(size_t)row * 64 + (t - 4) * 16 + m] = f2bf(c[t][r]);
            }
        }
    }
}

// ---------------- K3: edge phase (MFMA, R2 structure) ----------------
// 16 edges per wave. A-frag: h[m=lane&15][k=quad*8+j]. B-frag: W2[k][n=lane&15].
// C/D: row(m)=quad*4+reg, col(n)=lane&15. Global f32 atomics into Hn.
__global__ __launch_bounds__(256) void k_edge(
    const int* __restrict__ ei,
    const unsigned short* __restrict__ A, const unsigned short* __restrict__ Bm,
    const float* __restrict__ conv_w2, const float* __restrict__ conv_b2,
    float* __restrict__ Hn, int E) {
    int lane = threadIdx.x & 63;
    int wid  = blockIdx.x * (blockDim.x >> 6) + (threadIdx.x >> 6);
    int nw   = gridDim.x * (blockDim.x >> 6);
    int q = lane >> 4;
    int m = lane & 15;

    short8 wf[2][2];
#pragma unroll
    for (int s = 0; s < 2; s++)
#pragma unroll
        for (int t = 0; t < 2; t++)
#pragma unroll
            for (int j = 0; j < 8; j++)
                wf[s][t][j] = (short)f2bf(conv_w2[(s * 32 + q * 8 + j) * 32 + t * 16 + m]);
    float cb2a = conv_b2[m];
    float cb2b = conv_b2[16 + m];

    const int* srcp = ei;
    const int* dstp = ei + E;
    int ngroups = E >> 4;

    for (int gI = wid; gI < ngroups; gI += nw) {
        int e0 = gI << 4;
        int vd = dstp[e0 + m];
        int vs = srcp[e0 + m];
        floatx4 c0 = {0.f, 0.f, 0.f, 0.f};
        floatx4 c1 = {0.f, 0.f, 0.f, 0.f};
#pragma unroll
        for (int ks = 0; ks < 2; ks++) {
            uint4 av = *(const uint4*)(A  + (size_t)vd * 64 + ks * 32 + q * 8);
            uint4 bv = *(const uint4*)(Bm + (size_t)vs * 64 + ks * 32 + q * 8);
            unsigned au[4] = {av.x, av.y, av.z, av.w};
            unsigned bu[4] = {bv.x, bv.y, bv.z, bv.w};
            short8 ha;
#pragma unroll
            for (int i = 0; i < 4; i++) {
                float a0 = __uint_as_float(au[i] << 16);
                float a1 = __uint_as_float(au[i] & 0xffff0000u);
                float b0 = __uint_as_float(bu[i] << 16);
                float b1 = __uint_as_float(bu[i] & 0xffff0000u);
                float h0 = fmaxf(a0 + b0, 0.f);
                float h1v = fmaxf(a1 + b1, 0.f);
                ha[2 * i]     = (short)f2bf(h0);
                ha[2 * i + 1] = (short)f2bf(h1v);
            }
            c0 = __builtin_amdgcn_mfma_f32_16x16x32_bf16(ha, wf[ks][0], c0, 0, 0, 0);
            c1 = __builtin_amdgcn_mfma_f32_16x16x32_bf16(ha, wf[ks][1], c1, 0, 0, 0);
        }
#pragma unroll
        for (int r = 0; r < 4; r++) {
            int m2 = (q << 2) + r;
            int dd = __shfl(vd, m2, 64);
            float o0 = fast_tanh(c0[r] + cb2a);
            float o1 = fast_tanh(c1[r] + cb2b);
            unsafeAtomicAdd(&Hn[(size_t)dd * 32 + m], o0);
            unsafeAtomicAdd(&Hn[(size_t)dd * 32 + 16 + m], o1);
        }
    }

    // scalar tail (E % 16)
    int tail = E & 15;
    if (tail && wid == 0 && lane < tail) {
        int e = (E & ~15) + lane;
        int vd = dstp[e], vs = srcp[e];
        float h[64];
        for (int k = 0; k < 64; k++) {
            float a = __uint_as_float((unsigned)A[(size_t)vd * 64 + k] << 16);
            float b = __uint_as_float((unsigned)Bm[(size_t)vs * 64 + k] << 16);
            h[k] = fmaxf(a + b, 0.f);
        }
        for (int j = 0; j < 32; j++) {
            float acc = conv_b2[j];
            for (int k = 0; k < 64; k++) acc += h[k] * conv_w2[k * 32 + j];
            unsafeAtomicAdd(&Hn[(size_t)vd * 32 + j], fast_tanh(acc));
        }
    }
}

// ---------------- K4: pool Hn into graph accumulators ----------------
// batch is sorted; segmented running sum per (thread, channel), flush on change.
__global__ __launch_bounds__(256) void k_pool(const float* __restrict__ Hn,
                                              const int* __restrict__ batch,
                                              float* __restrict__ gacc, int N) {
    const int NPB = 512;
    int c = threadIdx.x & 31;
    int r = threadIdx.x >> 5;  // 0..7
    int n0 = blockIdx.x * NPB;
    int nend = min(n0 + NPB, N);
    int gcur = -1;
    float acc = 0.f;
    for (int n = n0 + r; n < nend; n += 8) {
        int g = batch[n];
        if (g != gcur) {
            if (gcur >= 0) unsafeAtomicAdd(&gacc[gcur * 46 + c], acc);
            gcur = g; acc = 0.f;
        }
        acc += Hn[(size_t)n * 32 + c];
    }
    if (gcur >= 0) unsafeAtomicAdd(&gacc[gcur * 46 + c], acc);
}

// ---------------- K5: output MLP ----------------
__global__ void k_out(const float* __restrict__ gacc,
                      const float* __restrict__ out_w1, const float* __restrict__ out_b1,
                      const float* __restrict__ out_w2, const float* __restrict__ out_b2,
                      float* __restrict__ out, int G) {
    int g = blockIdx.x * blockDim.x + threadIdx.x;
    if (g >= G) return;
    float cnt = fmaxf(gacc[g * 46 + 45], 1.0f);
    float inv = 1.0f / cnt;
    float f[45];
#pragma unroll
    for (int i = 0; i < 45; i++) f[i] = gacc[g * 46 + i] * inv;
    float h[32];
#pragma unroll
    for (int j = 0; j < 32; j++) {
        float acc = out_b1[j];
#pragma unroll
        for (int k = 0; k < 45; k++) acc += f[k] * out_w1[k * 32 + j];
        h[j] = fmaxf(acc, 0.f);
    }
    float o = out_b2[0];
#pragma unroll
    for (int j = 0; j < 32; j++) o += h[j] * out_w2[j];
    out[g] = fast_sigmoid(o);
}

extern "C" void kernel_launch(void* const* d_in, const int* in_sizes, int n_in,
                              void* d_out, int out_size, void* d_ws, size_t ws_size,
                              hipStream_t stream) {
    const float* x      = (const float*)d_in[0];
    const int*   ei     = (const int*)d_in[1];
    const int*   batch  = (const int*)d_in[2];
    const float* bn_g   = (const float*)d_in[3];
    const float* bn_b   = (const float*)d_in[4];
    const float* in_w1  = (const float*)d_in[5];
    const float* in_b1  = (const float*)d_in[6];
    const float* in_w2  = (const float*)d_in[7];
    const float* in_b2  = (const float*)d_in[8];
    const float* cw1    = (const float*)d_in[9];
    const float* cb1    = (const float*)d_in[10];
    const float* cw2    = (const float*)d_in[11];
    const float* cb2    = (const float*)d_in[12];
    const float* ow1    = (const float*)d_in[13];
    const float* ob1    = (const float*)d_in[14];
    const float* ow2    = (const float*)d_in[15];
    const float* ob2    = (const float*)d_in[16];

    int N = in_sizes[0] / 13;
    int E = in_sizes[1] / 2;
    int G = out_size;
    int Npad = (N + 255) & ~255;

    auto al = [](size_t v) { return (v + 255) & ~(size_t)255; };
    char* ws = (char*)d_ws;
    size_t hn_off   = 0;
    size_t gacc_off = al((size_t)N * 32 * 4);
    size_t bns_off  = gacc_off + al((size_t)G * 46 * 4);
    size_t scl_off  = bns_off + 256;
    size_t a_off    = scl_off + 256;
    size_t b_off    = a_off + al((size_t)Npad * 64 * 2);

    float* Hn   = (float*)(ws + hn_off);
    float* gacc = (float*)(ws + gacc_off);
    float* bns  = (float*)(ws + bns_off);
    float* scl  = (float*)(ws + scl_off);
    unsigned short* A  = (unsigned short*)(ws + a_off);
    unsigned short* Bm = (unsigned short*)(ws + b_off);

    // zero Hn + gacc + bn accumulators (ws is poisoned 0xAA before each call)
    hipMemsetAsync(ws, 0, bns_off + 256, stream);

    k_bnstat<<<120, 256, 0, stream>>>(x, N, bns);
    k_bnfin<<<1, 64, 0, stream>>>(bns, bn_g, bn_b, scl, 1.0f / (float)N);
    k_node<<<(N + 127) / 128, 128, 0, stream>>>(x, batch, in_w1, in_b1, in_w2, in_b2,
                                                cw1, cb1, scl, A, Bm, gacc, N);
    k_edge<<<1024, 256, 0, stream>>>(ei, A, Bm, cw2, cb2, Hn, E);
    k_pool<<<(N + 511) / 512, 256, 0, stream>>>(Hn, batch, gacc, N);
    k_out<<<1, 128, 0, stream>>>(gacc, ow1, ob1, ow2, ob2, (float*)d_out, G);
}

// Round 6
// 395.933 us; speedup vs baseline: 1.3380x; 1.1626x over previous
//
#include <hip/hip_runtime.h>

// EdgeNet: BN -> inputnet MLP -> EdgeConv(linearized) -> mean-pool -> output MLP
// N=50000, E=1.6M, D=13, H=32, G=128. All I/O float32.
// EdgeConv restructure: m = [x_i, x_j-x_i]@W1 = x_i@(Wtop-Wbot) + x_j@Wbot
//   => per-node A = feat@(Wtop-Wbot)+b1, B = feat@Wbot (bf16), per-edge
//      h = relu(A[dst]+B[src]); msg = tanh(h@W2+b2) via MFMA 16x16x32 bf16.
// R6: k_edge atomics halved via global_atomic_pk_add_bf16 (one packed op per
//     channel pair; W2 cols interleaved even/odd so lane m holds ch 2m,2m+1).
//     Hn is now bf16; k_pool converts on read, pools in f32. k_edge was at the
//     f32-atomic op-rate ceiling (51.2M ops / 169us = 303 G/s = TCC rate).

typedef __attribute__((ext_vector_type(4))) float floatx4;
typedef __attribute__((ext_vector_type(8))) short short8;

__device__ __forceinline__ unsigned short f2bf(float f) {
    unsigned int u = __float_as_uint(f);
    u += 0x7FFFu + ((u >> 16) & 1u);   // RTNE
    return (unsigned short)(u >> 16);
}
__device__ __forceinline__ float bf2f(unsigned short u) {
    return __uint_as_float(((unsigned int)u) << 16);
}
__device__ __forceinline__ float fast_tanh(float x) {
    float ax = fminf(fabsf(x), 20.0f);
    float t = __expf(-2.0f * ax);
    float r = (1.0f - t) / (1.0f + t);
    return copysignf(r, x);
}
__device__ __forceinline__ float fast_sigmoid(float x) {
    float xc = fminf(fmaxf(x, -30.f), 30.f);
    return 1.0f / (1.0f + __expf(-xc));
}
// fire-and-forget packed bf16x2 atomic add (memory-side RMW)
__device__ __forceinline__ void atomic_pk_add_bf16(unsigned short* addr, unsigned int packed) {
    asm volatile("global_atomic_pk_add_bf16 %0, %1, off" :: "v"(addr), "v"(packed) : "memory");
}

// ---------------- K1: BatchNorm statistics ----------------
__global__ __launch_bounds__(256) void k_bnstat(const float* __restrict__ x,
                                                int N, float* __restrict__ bns) {
    int tid = blockIdx.x * blockDim.x + threadIdx.x;
    int stride = gridDim.x * blockDim.x;
    float s[13], q[13];
#pragma unroll
    for (int d = 0; d < 13; d++) { s[d] = 0.f; q[d] = 0.f; }
    for (int n = tid; n < N; n += stride) {
        const float* row = x + (size_t)n * 13;
#pragma unroll
        for (int d = 0; d < 13; d++) { float f = row[d]; s[d] += f; q[d] += f * f; }
    }
#pragma unroll
    for (int d = 0; d < 13; d++) {
        for (int off = 32; off > 0; off >>= 1) {
            s[d] += __shfl_down(s[d], off, 64);
            q[d] += __shfl_down(q[d], off, 64);
        }
    }
    if ((threadIdx.x & 63) == 0) {
#pragma unroll
        for (int d = 0; d < 13; d++) {
            unsafeAtomicAdd(&bns[d], s[d]);
            unsafeAtomicAdd(&bns[13 + d], q[d]);
        }
    }
}

// ---------------- K1b: finalize scale/shift ----------------
__global__ void k_bnfin(const float* __restrict__ bns, const float* __restrict__ g,
                        const float* __restrict__ b, float* __restrict__ scl, float invN) {
    int d = threadIdx.x;
    if (d < 13) {
        float mu  = bns[d] * invN;
        float var = fmaxf(bns[13 + d] * invN - mu * mu, 0.f);
        float sc  = g[d] / sqrtf(var + 1e-5f);
        scl[d]      = sc;
        scl[16 + d] = b[d] - mu * sc;
    }
}

// ---------------- K2: per-node phase (128 threads / 128 nodes per block) ----
#define FP 72  // feat LDS row stride in shorts (64 + 8 pad)
#define WP 72  // WcatT LDS row stride in shorts
__global__ __launch_bounds__(128) void k_node(
    const float* __restrict__ x, const int* __restrict__ batch,
    const float* __restrict__ in_w1, const float* __restrict__ in_b1,
    const float* __restrict__ in_w2, const float* __restrict__ in_b2,
    const float* __restrict__ conv_w1, const float* __restrict__ conv_b1,
    const float* __restrict__ scl,
    unsigned short* __restrict__ A, unsigned short* __restrict__ Bm,
    float* __restrict__ gacc, int N) {
    __shared__ float sW1[13 * 32], sB1[32], sW2[32 * 32], sB2[32];
    __shared__ unsigned short sWcatT[128 * WP];  // [col c][k], bf16
    __shared__ unsigned short sFeat[128 * FP];   // [node row][k], bf16
    int tid = threadIdx.x;

    // ---- phase 0: weights to LDS ----
    for (int i = tid; i < 13 * 32; i += 128) sW1[i] = in_w1[i];
    if (tid < 32) { sB1[tid] = in_b1[tid]; sB2[tid] = in_b2[tid]; }
    for (int i = tid; i < 32 * 32; i += 128) sW2[i] = in_w2[i];
    // WcatT[c][k]: c<64 -> Wd[k][c]=top-bot ; c>=64 -> Wb[k][c-64]=bot ; k>=45 -> 0
    for (int i = tid; i < 128 * 64; i += 128) {
        int c = i >> 6, k = i & 63;
        float v = 0.f;
        if (k < 45) {
            int cc = c & 63;
            float bot = conv_w1[(45 + k) * 64 + cc];
            v = (c < 64) ? (conv_w1[k * 64 + cc] - bot) : bot;
        }
        sWcatT[c * WP + k] = f2bf(v);
    }
    __syncthreads();

    int n = blockIdx.x * 128 + tid;
    bool valid = (n < N);
    int nl = valid ? n : (N - 1);

    // ---- phase 1: per-thread MLP ----
    float X[13];
#pragma unroll
    for (int d = 0; d < 13; d++)
        X[d] = x[(size_t)nl * 13 + d] * scl[d] + scl[16 + d];
    float h1[32];
#pragma unroll
    for (int j = 0; j < 32; j++) {
        float acc = sB1[j];
#pragma unroll
        for (int d = 0; d < 13; d++) acc += X[d] * sW1[d * 32 + j];
        h1[j] = fmaxf(acc, 0.f);
    }
    float h2[32];
#pragma unroll
    for (int j = 0; j < 32; j++) {
        float acc = sB2[j];
#pragma unroll
        for (int k = 0; k < 32; k++) acc += h1[k] * sW2[k * 32 + j];
        h2[j] = fast_tanh(acc);
    }

    // feat row = [h2(32) | X(13) | zeros(19)] bf16 -> LDS
    unsigned int fw[16];
#pragma unroll
    for (int i = 0; i < 16; i++) fw[i] = 0;
    if (valid) {
#pragma unroll
        for (int i = 0; i < 16; i++)
            fw[i] = (unsigned)f2bf(h2[2 * i]) | ((unsigned)f2bf(h2[2 * i + 1]) << 16);
    }
    unsigned int xw[7];
#pragma unroll
    for (int i = 0; i < 7; i++) xw[i] = 0;
    if (valid) {
#pragma unroll
        for (int i = 0; i < 6; i++)
            xw[i] = (unsigned)f2bf(X[2 * i]) | ((unsigned)f2bf(X[2 * i + 1]) << 16);
        xw[6] = (unsigned)f2bf(X[12]);
    }
    {
        unsigned short* row = sFeat + tid * FP;
        ((uint4*)row)[0] = make_uint4(fw[0], fw[1], fw[2], fw[3]);
        ((uint4*)row)[1] = make_uint4(fw[4], fw[5], fw[6], fw[7]);
        ((uint4*)row)[2] = make_uint4(fw[8], fw[9], fw[10], fw[11]);
        ((uint4*)row)[3] = make_uint4(fw[12], fw[13], fw[14], fw[15]);
        ((uint4*)row)[4] = make_uint4(xw[0], xw[1], xw[2], xw[3]);
        ((uint4*)row)[5] = make_uint4(xw[4], xw[5], xw[6], 0u);
        ((uint4*)row)[6] = make_uint4(0u, 0u, 0u, 0u);
        ((uint4*)row)[7] = make_uint4(0u, 0u, 0u, 0u);
    }

    // ---- gacc: graph sums of X + count (wave-reduced when graph-uniform) ----
    {
        int g = valid ? batch[n] : -1;
        unsigned long long uni = __ballot(g == __shfl(g, 0, 64));
        if (uni == ~0ull && g >= 0) {
            float red[14];
#pragma unroll
            for (int d = 0; d < 13; d++) red[d] = X[d];
            red[13] = 1.0f;
#pragma unroll
            for (int d = 0; d < 14; d++)
                for (int off = 32; off > 0; off >>= 1)
                    red[d] += __shfl_down(red[d], off, 64);
            if ((tid & 63) == 0) {
#pragma unroll
                for (int d = 0; d < 13; d++) unsafeAtomicAdd(&gacc[g * 46 + 32 + d], red[d]);
                unsafeAtomicAdd(&gacc[g * 46 + 45], red[13]);
            }
        } else if (valid) {
#pragma unroll
            for (int d = 0; d < 13; d++) unsafeAtomicAdd(&gacc[g * 46 + 32 + d], X[d]);
            unsafeAtomicAdd(&gacc[g * 46 + 45], 1.0f);
        }
    }
    __syncthreads();

    // ---- phase 2: MFMA feat@Wcat (2 waves, 4 row-tiles each) ----
    int lane = tid & 63;
    int w = tid >> 6;        // wave id 0..1
    int q = lane >> 4;
    int m = lane & 15;

    short8 wf[2][8];  // [ks][col-tile]
#pragma unroll
    for (int ks = 0; ks < 2; ks++)
#pragma unroll
        for (int t = 0; t < 8; t++) {
            wf[ks][t] = *(const short8*)(sWcatT + (t * 16 + m) * WP + ks * 32 + q * 8);
        }
    float cb1v[4];
#pragma unroll
    for (int t = 0; t < 4; t++) cb1v[t] = conv_b1[t * 16 + m];

    int base = blockIdx.x * 128 + w * 64;
#pragma unroll
    for (int tile = 0; tile < 4; tile++) {
        const unsigned short* ar = sFeat + (w * 64 + tile * 16 + m) * FP;
        short8 a0 = *(const short8*)(ar + q * 8);
        short8 a1 = *(const short8*)(ar + 32 + q * 8);
        floatx4 c[8];
#pragma unroll
        for (int t = 0; t < 8; t++) {
            floatx4 z = {0.f, 0.f, 0.f, 0.f};
            c[t] = __builtin_amdgcn_mfma_f32_16x16x32_bf16(a0, wf[0][t], z, 0, 0, 0);
            c[t] = __builtin_amdgcn_mfma_f32_16x16x32_bf16(a1, wf[1][t], c[t], 0, 0, 0);
        }
        // C/D: col=m (within tile), row=q*4+r
#pragma unroll
        for (int r = 0; r < 4; r++) {
            int row = base + tile * 16 + (q << 2) + r;
            if (row < N) {
#pragma unroll
                for (int t = 0; t < 4; t++)
                    A[(size_t)row * 64 + t * 16 + m] = f2bf(c[t][r] + cb1v[t]);
#pragma unroll
                for (int t = 4; t < 8; t++)
                    Bm[(size_t)row * 64 + (t - 4) * 16 + m] = f2bf(c[t][r]);
            }
        }
    }
}

// ---------------- K3: edge phase (MFMA + packed bf16 atomics) ----------------
// 16 edges per wave. A-frag: h[m=lane&15][k=q*8+j]. B-frags hold W2 cols
// interleaved even/odd (tile0 col n -> 2n, tile1 -> 2n+1) so lane m's two C
// values are channels (2m, 2m+1) -> ONE global_atomic_pk_add_bf16 per pair.
__global__ __launch_bounds__(256) void k_edge(
    const int* __restrict__ ei,
    const unsigned short* __restrict__ A, const unsigned short* __restrict__ Bm,
    const float* __restrict__ conv_w2, const float* __restrict__ conv_b2,
    unsigned short* __restrict__ Hn, int E) {
    int lane = threadIdx.x & 63;
    int wid  = blockIdx.x * (blockDim.x >> 6) + (threadIdx.x >> 6);
    int nw   = gridDim.x * (blockDim.x >> 6);
    int q = lane >> 4;
    int m = lane & 15;

    short8 wf[2][2];
#pragma unroll
    for (int s = 0; s < 2; s++)
#pragma unroll
        for (int t = 0; t < 2; t++)
#pragma unroll
            for (int j = 0; j < 8; j++)
                wf[s][t][j] = (short)f2bf(conv_w2[(s * 32 + q * 8 + j) * 32 + 2 * m + t]);
    float cb2a = conv_b2[2 * m];
    float cb2b = conv_b2[2 * m + 1];

    const int* srcp = ei;
    const int* dstp = ei + E;
    int ngroups = E >> 4;

    for (int gI = wid; gI < ngroups; gI += nw) {
        int e0 = gI << 4;
        int vd = dstp[e0 + m];
        int vs = srcp[e0 + m];
        floatx4 c0 = {0.f, 0.f, 0.f, 0.f};
        floatx4 c1 = {0.f, 0.f, 0.f, 0.f};
#pragma unroll
        for (int ks = 0; ks < 2; ks++) {
            uint4 av = *(const uint4*)(A  + (size_t)vd * 64 + ks * 32 + q * 8);
            uint4 bv = *(const uint4*)(Bm + (size_t)vs * 64 + ks * 32 + q * 8);
            unsigned au[4] = {av.x, av.y, av.z, av.w};
            unsigned bu[4] = {bv.x, bv.y, bv.z, bv.w};
            short8 ha;
#pragma unroll
            for (int i = 0; i < 4; i++) {
                float a0 = __uint_as_float(au[i] << 16);
                float a1 = __uint_as_float(au[i] & 0xffff0000u);
                float b0 = __uint_as_float(bu[i] << 16);
                float b1 = __uint_as_float(bu[i] & 0xffff0000u);
                float h0 = fmaxf(a0 + b0, 0.f);
                float h1v = fmaxf(a1 + b1, 0.f);
                ha[2 * i]     = (short)f2bf(h0);
                ha[2 * i + 1] = (short)f2bf(h1v);
            }
            c0 = __builtin_amdgcn_mfma_f32_16x16x32_bf16(ha, wf[ks][0], c0, 0, 0, 0);
            c1 = __builtin_amdgcn_mfma_f32_16x16x32_bf16(ha, wf[ks][1], c1, 0, 0, 0);
        }
#pragma unroll
        for (int r = 0; r < 4; r++) {
            int m2 = (q << 2) + r;
            int dd = __shfl(vd, m2, 64);
            float o0 = fast_tanh(c0[r] + cb2a);
            float o1 = fast_tanh(c1[r] + cb2b);
            unsigned int pk = (unsigned)f2bf(o0) | ((unsigned)f2bf(o1) << 16);
            atomic_pk_add_bf16(Hn + (size_t)dd * 32 + 2 * m, pk);
        }
    }

    // scalar tail (E % 16): packed pairs too
    int tail = E & 15;
    if (tail && wid == 0 && lane < tail) {
        int e = (E & ~15) + lane;
        int vd = dstp[e], vs = srcp[e];
        float h[64];
        for (int k = 0; k < 64; k++) {
            float a = bf2f(A[(size_t)vd * 64 + k]);
            float b = bf2f(Bm[(size_t)vs * 64 + k]);
            h[k] = fmaxf(a + b, 0.f);
        }
        for (int j = 0; j < 16; j++) {
            float acc0 = conv_b2[2 * j], acc1 = conv_b2[2 * j + 1];
            for (int k = 0; k < 64; k++) {
                acc0 += h[k] * conv_w2[k * 32 + 2 * j];
                acc1 += h[k] * conv_w2[k * 32 + 2 * j + 1];
            }
            unsigned int pk = (unsigned)f2bf(fast_tanh(acc0)) | ((unsigned)f2bf(fast_tanh(acc1)) << 16);
            atomic_pk_add_bf16(Hn + (size_t)vd * 32 + 2 * j, pk);
        }
    }
}

// ---------------- K4: pool bf16 Hn into graph accumulators ----------------
// batch is sorted; segmented running sum per (thread, channel), flush on change.
__global__ __launch_bounds__(256) void k_pool(const unsigned short* __restrict__ Hn,
                                              const int* __restrict__ batch,
                                              float* __restrict__ gacc, int N) {
    const int NPB = 512;
    int c = threadIdx.x & 31;
    int r = threadIdx.x >> 5;  // 0..7
    int n0 = blockIdx.x * NPB;
    int nend = min(n0 + NPB, N);
    int gcur = -1;
    float acc = 0.f;
    for (int n = n0 + r; n < nend; n += 8) {
        int g = batch[n];
        if (g != gcur) {
            if (gcur >= 0) unsafeAtomicAdd(&gacc[gcur * 46 + c], acc);
            gcur = g; acc = 0.f;
        }
        acc += bf2f(Hn[(size_t)n * 32 + c]);
    }
    if (gcur >= 0) unsafeAtomicAdd(&gacc[gcur * 46 + c], acc);
}

// ---------------- K5: output MLP ----------------
__global__ void k_out(const float* __restrict__ gacc,
                      const float* __restrict__ out_w1, const float* __restrict__ out_b1,
                      const float* __restrict__ out_w2, const float* __restrict__ out_b2,
                      float* __restrict__ out, int G) {
    int g = blockIdx.x * blockDim.x + threadIdx.x;
    if (g >= G) return;
    float cnt = fmaxf(gacc[g * 46 + 45], 1.0f);
    float inv = 1.0f / cnt;
    float f[45];
#pragma unroll
    for (int i = 0; i < 45; i++) f[i] = gacc[g * 46 + i] * inv;
    float h[32];
#pragma unroll
    for (int j = 0; j < 32; j++) {
        float acc = out_b1[j];
#pragma unroll
        for (int k = 0; k < 45; k++) acc += f[k] * out_w1[k * 32 + j];
        h[j] = fmaxf(acc, 0.f);
    }
    float o = out_b2[0];
#pragma unroll
    for (int j = 0; j < 32; j++) o += h[j] * out_w2[j];
    out[g] = fast_sigmoid(o);
}

extern "C" void kernel_launch(void* const* d_in, const int* in_sizes, int n_in,
                              void* d_out, int out_size, void* d_ws, size_t ws_size,
                              hipStream_t stream) {
    const float* x      = (const float*)d_in[0];
    const int*   ei     = (const int*)d_in[1];
    const int*   batch  = (const int*)d_in[2];
    const float* bn_g   = (const float*)d_in[3];
    const float* bn_b   = (const float*)d_in[4];
    const float* in_w1  = (const float*)d_in[5];
    const float* in_b1  = (const float*)d_in[6];
    const float* in_w2  = (const float*)d_in[7];
    const float* in_b2  = (const float*)d_in[8];
    const float* cw1    = (const float*)d_in[9];
    const float* cb1    = (const float*)d_in[10];
    const float* cw2    = (const float*)d_in[11];
    const float* cb2    = (const float*)d_in[12];
    const float* ow1    = (const float*)d_in[13];
    const float* ob1    = (const float*)d_in[14];
    const float* ow2    = (const float*)d_in[15];
    const float* ob2    = (const float*)d_in[16];

    int N = in_sizes[0] / 13;
    int E = in_sizes[1] / 2;
    int G = out_size;
    int Npad = (N + 255) & ~255;

    auto al = [](size_t v) { return (v + 255) & ~(size_t)255; };
    char* ws = (char*)d_ws;
    size_t hn_off   = 0;                                  // Hn: bf16 [N][32]
    size_t gacc_off = al((size_t)N * 32 * 2);
    size_t bns_off  = gacc_off + al((size_t)G * 46 * 4);
    size_t scl_off  = bns_off + 256;
    size_t a_off    = scl_off + 256;
    size_t b_off    = a_off + al((size_t)Npad * 64 * 2);

    unsigned short* Hn = (unsigned short*)(ws + hn_off);
    float* gacc = (float*)(ws + gacc_off);
    float* bns  = (float*)(ws + bns_off);
    float* scl  = (float*)(ws + scl_off);
    unsigned short* A  = (unsigned short*)(ws + a_off);
    unsigned short* Bm = (unsigned short*)(ws + b_off);

    // zero Hn (bf16 0x0000 == +0.0) + gacc + bn accumulators
    hipMemsetAsync(ws, 0, bns_off + 256, stream);

    k_bnstat<<<120, 256, 0, stream>>>(x, N, bns);
    k_bnfin<<<1, 64, 0, stream>>>(bns, bn_g, bn_b, scl, 1.0f / (float)N);
    k_node<<<(N + 127) / 128, 128, 0, stream>>>(x, batch, in_w1, in_b1, in_w2, in_b2,
                                                cw1, cb1, scl, A, Bm, gacc, N);
    k_edge<<<1024, 256, 0, stream>>>(ei, A, Bm, cw2, cb2, Hn, E);
    k_pool<<<(N + 511) / 512, 256, 0, stream>>>(Hn, batch, gacc, N);
    k_out<<<1, 128, 0, stream>>>(gacc, ow1, ob1, ow2, ob2, (float*)d_out, G);
}